// Round 1
// baseline (353.873 us; speedup 1.0000x reference)
//
#include <hip/hip_runtime.h>

// Unpack padded [B=8, Lmax=4096, H=16, D=128] fp32 -> packed [N, H, D].
// Each output row n is a contiguous 2048-float (8 KB) copy from src row
// (b, t) where b = searchsorted(cumsum(lengths), n, 'right'), t = n - start[b].
// Pure streaming gather: memory-bound, target HBM BW ceiling.

#define ROW_F4 512   // floats per row / 4 = (16*128)/4
#define LMAX   4096
#define BATCH  8

__global__ __launch_bounds__(256) void unpack_rows_kernel(
    const float4* __restrict__ src,
    const int*    __restrict__ lengths,
    float4*       __restrict__ dst,
    int n4)   // total float4 elements in output
{
    // Exclusive-end cumsum of lengths, in registers (8 broadcast loads,
    // L1-served; loop-invariant w.r.t. the grid-stride loop below).
    int ends[BATCH];
    int c = 0;
#pragma unroll
    for (int j = 0; j < BATCH; ++j) {
        c += lengths[j];
        ends[j] = c;
    }

    const int stride = gridDim.x * blockDim.x;
    for (int i = blockIdx.x * blockDim.x + threadIdx.x; i < n4; i += stride) {
        const int n   = i >> 9;      // output row   (512 float4 per row)
        const int off = i & (ROW_F4 - 1);

        // b = #{j : ends[j] <= n}; st = ends[b-1] (0 if b==0).
        // Fully-unrolled select chain — stays in registers, no divergence.
        int b = 0, st = 0;
#pragma unroll
        for (int j = 0; j < BATCH; ++j) {
            const bool ge = (n >= ends[j]);
            b  = ge ? (j + 1)  : b;
            st = ge ? ends[j]  : st;
        }
        const int t = n - st;

        // src float4 index: ((b*Lmax + t) * 512 + off); max 16.7M, fits int.
        const int srcIdx = ((b << 12) + t) * ROW_F4 + off;
        dst[i] = src[srcIdx];
    }
}

extern "C" void kernel_launch(void* const* d_in, const int* in_sizes, int n_in,
                              void* d_out, int out_size, void* d_ws, size_t ws_size,
                              hipStream_t stream) {
    const float4* src     = (const float4*)d_in[0];
    const int*    lengths = (const int*)d_in[1];
    float4*       dst     = (float4*)d_out;

    const int n4 = out_size / 4;          // out_size = N * 2048, divisible by 4
    const int block = 256;
    int grid = (n4 + block - 1) / block;
    if (grid > 16384) grid = 16384;       // grid-stride; ~2 iters/thread at N~16K
    if (grid < 1) grid = 1;

    unpack_rows_kernel<<<grid, block, 0, stream>>>(src, lengths, dst, n4);
}

// Round 3
// 350.426 us; speedup vs baseline: 1.0098x; 1.0098x over previous
//
#include <hip/hip_runtime.h>

// Unpack padded [B=8, Lmax=4096, H=16, D=128] fp32 -> packed [N, H, D].
// Pure streaming gather-copy: each output row n is a contiguous 8 KB chunk
// src[b, t] where b = searchsorted(cumsum(lengths), n), t = n - start[b].
// Memory-bound; target HBM BW ceiling (~6.3 TB/s achievable).
//
// Layout facts: row = H*D = 2048 floats = 512 float4. One 16 B vector per
// thread, exactly one load + one store, both perfectly coalesced. Nontemporal
// hints: both streams are touch-once and exceed the 32 MB aggregate L2.
// NOTE: __builtin_nontemporal_* requires a native clang vector type, not
// HIP's float4 struct — use ext_vector_type(4).

#define BATCH  8
#define ROW_F4 512    // (16*128)/4 vectors per row

typedef float f4 __attribute__((ext_vector_type(4)));

__global__ __launch_bounds__(256) void unpack_rows_kernel(
    const f4* __restrict__ src,
    const int* __restrict__ lengths,
    f4*       __restrict__ dst,
    int n4)   // total 16B-vector count in output = N * 512
{
    const int i = blockIdx.x * 256 + threadIdx.x;
    if (i >= n4) return;

    // Exclusive-end cumsum of lengths (uniform; compiler scalarizes these).
    int ends[BATCH];
    int c = 0;
#pragma unroll
    for (int j = 0; j < BATCH; ++j) {
        c += lengths[j];
        ends[j] = c;
    }

    const int n   = i >> 9;           // output row index
    const int off = i & (ROW_F4 - 1); // vector offset within the row

    // b = #{j : ends[j] <= n}; st = ends[b-1] (0 if b==0). Unrolled select
    // chain, registers only, no divergence.
    int b = 0, st = 0;
#pragma unroll
    for (int j = 0; j < BATCH; ++j) {
        const bool ge = (n >= ends[j]);
        b  = ge ? (j + 1) : b;
        st = ge ? ends[j] : st;
    }
    const int t = n - st;

    // src vector index: (b*4096 + t)*512 + off; max ~16.7M, fits in int.
    const f4 v = __builtin_nontemporal_load(&src[((b << 12) + t) * ROW_F4 + off]);
    __builtin_nontemporal_store(v, &dst[i]);
}

extern "C" void kernel_launch(void* const* d_in, const int* in_sizes, int n_in,
                              void* d_out, int out_size, void* d_ws, size_t ws_size,
                              hipStream_t stream) {
    const f4*  src     = (const f4*)d_in[0];
    const int* lengths = (const int*)d_in[1];
    f4*        dst     = (f4*)d_out;

    const int n4 = out_size / 4;                 // out_size = N*2048, /4 exact
    const int block = 256;
    const int grid  = (n4 + block - 1) / block;  // 1 vector per thread

    if (grid > 0)
        unpack_rows_kernel<<<grid, block, 0, stream>>>(src, lengths, dst, n4);
}